// Round 1
// baseline (505.570 us; speedup 1.0000x reference)
//
#include <hip/hip_runtime.h>

// HeavySnow: stamp flakes (0.95 squares, all channels) -> depthwise 5x5
// gaussian blur (zero pad) -> clip [0,1].
// Strategy: 1-bit/pixel flake mask in d_ws (channel-shared, 2 MB total),
// then one fused tiled separable-blur kernel reading x + mask, writing out.
// This avoids materializing the stamped image (saves a 402 MB copy pass).

#define H_ 1024
#define W_ 1024
#define B_ 16
#define C_ 3
#define NF_ 15728
#define MASK_WORDS_PER_B (H_ * W_ / 32)  // 32768 words (128 KB) per batch

// Gaussian weights: sigma=1.5, K=5, normalized. g = [g0,g1,g2,g1,g0].
#define G0 0.12007838f
#define G1 0.23388076f
#define G2 0.29208172f

__global__ void clear_mask_kernel(unsigned int* __restrict__ mask, int n) {
    int i = blockIdx.x * blockDim.x + threadIdx.x;
    if (i < n) mask[i] = 0u;
}

__global__ void stamp_kernel(const int* __restrict__ ys, const int* __restrict__ xs,
                             const int* __restrict__ rs, unsigned int* __restrict__ mask) {
    int t = blockIdx.x * blockDim.x + threadIdx.x;
    if (t >= B_ * NF_) return;
    int b = t / NF_;
    int y0 = ys[t], x0 = xs[t], r = rs[t];
    unsigned int* mb = mask + b * MASK_WORDS_PER_B;
    // Reference clips coords to bounds; net effect = stamp the in-bounds part
    // of the (2r+1)^2 square (border pixels already covered by in-range offsets).
    int xlo = max(x0 - r, 0), xhi = min(x0 + r, W_ - 1);
    int ylo = max(y0 - r, 0), yhi = min(y0 + r, H_ - 1);
    for (int y = ylo; y <= yhi; ++y) {
        int i0 = (y << 10) + xlo;
        int i1 = (y << 10) + xhi;
        int w0 = i0 >> 5, w1 = i1 >> 5;
        unsigned int m0 = ~0u << (i0 & 31);
        unsigned int m1 = ~0u >> (31 - (i1 & 31));
        if (w0 == w1) {
            atomicOr(mb + w0, m0 & m1);
        } else {
            atomicOr(mb + w0, m0);
            atomicOr(mb + w1, m1);
        }
    }
}

// Tiled separable 5x5 blur, fused with flake substitution and clip.
// Tile: 128 wide x 32 high; halo 2 each side -> load 132x36 into LDS.
constexpr int TW = 128;
constexpr int TH = 32;

__global__ __launch_bounds__(256) void blur_kernel(const float* __restrict__ x,
                                                   const unsigned int* __restrict__ mask,
                                                   float* __restrict__ out) {
    int plane = blockIdx.z;            // b*C + c
    int b = plane / C_;
    const float* xp = x + (size_t)plane * (H_ * W_);
    float* op = out + (size_t)plane * (H_ * W_);
    const unsigned int* mb = mask + b * MASK_WORDS_PER_B;

    int tx0 = blockIdx.x * TW;
    int ty0 = blockIdx.y * TH;

    __shared__ float sin_[(TH + 4)][(TW + 4)];  // 36 x 132
    __shared__ float smid[(TH + 4)][TW];        // 36 x 128

    // ---- load tile + halo, substituting 0.95 where mask bit set; OOB -> 0 ----
    for (int i = threadIdx.x; i < (TH + 4) * (TW + 4); i += 256) {
        int r = i / (TW + 4);
        int c = i % (TW + 4);
        int gy = ty0 + r - 2;
        int gx = tx0 + c - 2;
        float v = 0.0f;
        if ((unsigned)gy < (unsigned)H_ && (unsigned)gx < (unsigned)W_) {
            int idx = (gy << 10) + gx;
            v = xp[idx];
            if ((mb[idx >> 5] >> (idx & 31)) & 1u) v = 0.95f;
        }
        sin_[r][c] = v;
    }
    __syncthreads();

    // ---- horizontal pass: 36 rows x 128 cols ----
    for (int i = threadIdx.x; i < (TH + 4) * TW; i += 256) {
        int r = i >> 7;          // / 128
        int c = i & (TW - 1);    // % 128
        const float* row = &sin_[r][c];
        smid[r][c] = G0 * (row[0] + row[4]) + G1 * (row[1] + row[3]) + G2 * row[2];
    }
    __syncthreads();

    // ---- vertical pass + clip + store: 32 x 128 ----
    for (int i = threadIdx.x; i < TH * TW; i += 256) {
        int r = i >> 7;
        int c = i & (TW - 1);
        float v = G0 * (smid[r][c] + smid[r + 4][c]) +
                  G1 * (smid[r + 1][c] + smid[r + 3][c]) +
                  G2 * (smid[r + 2][c]);
        v = fminf(fmaxf(v, 0.0f), 1.0f);
        op[((ty0 + r) << 10) + tx0 + c] = v;
    }
}

extern "C" void kernel_launch(void* const* d_in, const int* in_sizes, int n_in,
                              void* d_out, int out_size, void* d_ws, size_t ws_size,
                              hipStream_t stream) {
    const float* x  = (const float*)d_in[0];
    const int*   ys = (const int*)d_in[1];
    const int*   xs = (const int*)d_in[2];
    const int*   rs = (const int*)d_in[3];
    float* out = (float*)d_out;
    unsigned int* mask = (unsigned int*)d_ws;  // 16 * 32768 words = 2 MB

    int nmask = B_ * MASK_WORDS_PER_B;
    clear_mask_kernel<<<dim3((nmask + 255) / 256), dim3(256), 0, stream>>>(mask, nmask);

    int nst = B_ * NF_;
    stamp_kernel<<<dim3((nst + 255) / 256), dim3(256), 0, stream>>>(ys, xs, rs, mask);

    dim3 grid(W_ / TW, H_ / TH, B_ * C_);
    blur_kernel<<<grid, dim3(256), 0, stream>>>(x, mask, out);
}

// Round 2
// 404.340 us; speedup vs baseline: 1.2504x; 1.2504x over previous
//
#include <hip/hip_runtime.h>

// HeavySnow: stamp flakes (0.95 squares, all channels) -> depthwise 5x5
// gaussian blur (zero pad) -> clip [0,1].
// R2: fully float4-vectorized blur; mask words staged in LDS (1 load/32 px).

#define H_ 1024
#define W_ 1024
#define B_ 16
#define C_ 3
#define NF_ 15728
#define MASK_WORDS_PER_B (H_ * W_ / 32)  // 32768 words (128 KB) per batch

// Gaussian weights: sigma=1.5, K=5, normalized. g = [g0,g1,g2,g1,g0].
#define G0 0.12007838f
#define G1 0.23388076f
#define G2 0.29208172f

__global__ void clear_mask_kernel(uint4* __restrict__ mask, int n4) {
    int i = blockIdx.x * blockDim.x + threadIdx.x;
    if (i < n4) mask[i] = make_uint4(0u, 0u, 0u, 0u);
}

__global__ void stamp_kernel(const int* __restrict__ ys, const int* __restrict__ xs,
                             const int* __restrict__ rs, unsigned int* __restrict__ mask) {
    int t = blockIdx.x * blockDim.x + threadIdx.x;
    if (t >= B_ * NF_) return;
    int b = t / NF_;
    int y0 = ys[t], x0 = xs[t], r = rs[t];
    unsigned int* mb = mask + b * MASK_WORDS_PER_B;
    int xlo = max(x0 - r, 0), xhi = min(x0 + r, W_ - 1);
    int ylo = max(y0 - r, 0), yhi = min(y0 + r, H_ - 1);
    for (int y = ylo; y <= yhi; ++y) {
        int i0 = (y << 10) + xlo;
        int i1 = (y << 10) + xhi;
        int w0 = i0 >> 5, w1 = i1 >> 5;
        unsigned int m0 = ~0u << (i0 & 31);
        unsigned int m1 = ~0u >> (31 - (i1 & 31));
        if (w0 == w1) {
            atomicOr(mb + w0, m0 & m1);
        } else {
            atomicOr(mb + w0, m0);
            atomicOr(mb + w1, m1);
        }
    }
}

// Tiled separable 5x5 blur, fused with flake substitution and clip.
// Output tile: 128 wide (32 float4) x 32 high. Halo 2 each side.
// LDS input staged as float4 with 4-col halo alignment: cols tx0-4 .. tx0+131.
constexpr int TW = 128;
constexpr int TH = 32;

__global__ __launch_bounds__(256) void blur_kernel(const float* __restrict__ x,
                                                   const unsigned int* __restrict__ mask,
                                                   float* __restrict__ out) {
    int plane = blockIdx.z;            // b*C + c
    int b = plane / C_;
    const float* xp = x + (size_t)plane * (H_ * W_);
    float* op = out + (size_t)plane * (H_ * W_);
    const unsigned int* mb = mask + b * MASK_WORDS_PER_B;

    const int tx0 = blockIdx.x * TW;
    const int ty0 = blockIdx.y * TH;
    const int tid = threadIdx.x;

    __shared__ float4 sin4[TH + 4][34];        // rows 36, scalar cols tx0-4 .. tx0+131
    __shared__ float4 smid4[TH + 4][32];       // h-filtered, cols tx0 .. tx0+127
    __shared__ unsigned int mrow[TH + 4][6];   // mask words covering tx0-32 .. tx0+159

    // ---- phase 0: stage mask words (one global dword per 32 pixels) ----
    const int w0 = (tx0 >> 5) - 1;
    for (int i = tid; i < (TH + 4) * 6; i += 256) {
        int r = i / 6, w = i % 6;
        int gy = ty0 + r - 2;
        int cw = w0 + w;
        unsigned int m = 0u;
        if ((unsigned)gy < (unsigned)H_ && (unsigned)cw < (unsigned)(W_ / 32))
            m = mb[(gy << 5) + cw];
        mrow[r][w] = m;
    }
    __syncthreads();

    // ---- phase 1: float4 load + flake substitution ----
    for (int i = tid; i < (TH + 4) * 34; i += 256) {
        int r = i / 34, j = i % 34;
        int gy = ty0 + r - 2;
        int gx4 = tx0 - 4 + 4 * j;             // 4-aligned
        float4 v = make_float4(0.f, 0.f, 0.f, 0.f);
        if ((unsigned)gy < (unsigned)H_ && (unsigned)gx4 < (unsigned)W_) {
            v = *(const float4*)(xp + (gy << 10) + gx4);
            unsigned int mw = mrow[r][(gx4 - tx0 + 32) >> 5];
            int bit = gx4 & 31;
            if ((mw >> (bit + 0)) & 1u) v.x = 0.95f;
            if ((mw >> (bit + 1)) & 1u) v.y = 0.95f;
            if ((mw >> (bit + 2)) & 1u) v.z = 0.95f;
            if ((mw >> (bit + 3)) & 1u) v.w = 0.95f;
        }
        sin4[r][j] = v;
    }
    __syncthreads();

    // ---- phase 2: horizontal pass, float4 outputs ----
    for (int i = tid; i < (TH + 4) * 32; i += 256) {
        int r = i >> 5;
        int j = i & 31;
        // scalar cols needed: s2..s9 relative to 4j (block-local); sits in sin4[r][j..j+2]
        float2 A = *(const float2*)((const float*)&sin4[r][j] + 2);     // s2,s3
        float4 Bv = sin4[r][j + 1];                                      // s4..s7
        float2 Cv = *(const float2*)((const float*)&sin4[r][j + 2]);     // s8,s9
        float4 o;
        o.x = G0 * (A.x  + Bv.z) + G1 * (A.y  + Bv.y) + G2 * Bv.x;
        o.y = G0 * (A.y  + Bv.w) + G1 * (Bv.x + Bv.z) + G2 * Bv.y;
        o.z = G0 * (Bv.x + Cv.x) + G1 * (Bv.y + Bv.w) + G2 * Bv.z;
        o.w = G0 * (Bv.y + Cv.y) + G1 * (Bv.z + Cv.x) + G2 * Bv.w;
        smid4[r][j] = o;
    }
    __syncthreads();

    // ---- phase 3: vertical pass + clip + float4 store ----
    for (int i = tid; i < TH * 32; i += 256) {
        int rr = i >> 5;
        int j = i & 31;
        float4 a0 = smid4[rr][j];
        float4 a1 = smid4[rr + 1][j];
        float4 a2 = smid4[rr + 2][j];
        float4 a3 = smid4[rr + 3][j];
        float4 a4 = smid4[rr + 4][j];
        float4 o;
        o.x = G0 * (a0.x + a4.x) + G1 * (a1.x + a3.x) + G2 * a2.x;
        o.y = G0 * (a0.y + a4.y) + G1 * (a1.y + a3.y) + G2 * a2.y;
        o.z = G0 * (a0.z + a4.z) + G1 * (a1.z + a3.z) + G2 * a2.z;
        o.w = G0 * (a0.w + a4.w) + G1 * (a1.w + a3.w) + G2 * a2.w;
        o.x = fminf(fmaxf(o.x, 0.0f), 1.0f);
        o.y = fminf(fmaxf(o.y, 0.0f), 1.0f);
        o.z = fminf(fmaxf(o.z, 0.0f), 1.0f);
        o.w = fminf(fmaxf(o.w, 0.0f), 1.0f);
        *(float4*)(op + ((ty0 + rr) << 10) + tx0 + 4 * j) = o;
    }
}

extern "C" void kernel_launch(void* const* d_in, const int* in_sizes, int n_in,
                              void* d_out, int out_size, void* d_ws, size_t ws_size,
                              hipStream_t stream) {
    const float* x  = (const float*)d_in[0];
    const int*   ys = (const int*)d_in[1];
    const int*   xs = (const int*)d_in[2];
    const int*   rs = (const int*)d_in[3];
    float* out = (float*)d_out;
    unsigned int* mask = (unsigned int*)d_ws;  // 16 * 32768 words = 2 MB

    int n4 = B_ * MASK_WORDS_PER_B / 4;
    clear_mask_kernel<<<dim3((n4 + 255) / 256), dim3(256), 0, stream>>>((uint4*)mask, n4);

    int nst = B_ * NF_;
    stamp_kernel<<<dim3((nst + 255) / 256), dim3(256), 0, stream>>>(ys, xs, rs, mask);

    dim3 grid(W_ / TW, H_ / TH, B_ * C_);
    blur_kernel<<<grid, dim3(256), 0, stream>>>(x, mask, out);
}